// Round 6
// baseline (17377.344 us; speedup 1.0000x reference)
//
#include <hip/hip_runtime.h>
#include <stdint.h>
#include <string.h>

#define NBATCH 8
#define NSPK_  4
#define DIMS   512
#define TLEN   2000
#define KC     4
#define NPTS   8000            // points per batch
#define NBLK   1000            // Lloyd / dist grid
#define NTHR   256
#define PPB    64              // points per block
#define BPB    125             // blocks per batch
#define MAXIT  100
#define TS     33              // k_iter LDS tile row stride (d-major)

#define THREEFRY_PARTITIONABLE 1

struct RArg { float r[3][NBATCH]; };

// ---- exact replica of numpy pairwise_sum (umath loops), stride in elements ----
__device__ float np_pw(const float* a, int n, int st){
  #pragma clang fp contract(off)
  if (n < 8){
    float r = 0.f;
    for (int i = 0; i < n; ++i) r += a[(long)i*st];
    return r;
  }
  if (n <= 128){
    float r0=a[0], r1=a[st], r2=a[2*st], r3=a[3*st],
          r4=a[4*st], r5=a[5*st], r6=a[6*st], r7=a[7*st];
    int i = 8;
    for (; i < n - (n & 7); i += 8){
      r0 += a[(long)(i+0)*st]; r1 += a[(long)(i+1)*st];
      r2 += a[(long)(i+2)*st]; r3 += a[(long)(i+3)*st];
      r4 += a[(long)(i+4)*st]; r5 += a[(long)(i+5)*st];
      r6 += a[(long)(i+6)*st]; r7 += a[(long)(i+7)*st];
    }
    float res = ((r0 + r1) + (r2 + r3)) + ((r4 + r5) + (r6 + r7));
    for (; i < n; ++i) res += a[(long)i*st];
    return res;
  }
  int n2 = n/2; n2 -= (n2 & 7);
  return np_pw(a, n2, st) + np_pw(a + (long)n2*st, n - n2, st);
}
__device__ float np_pw_sq(const float* a, int n, int st){
  #pragma clang fp contract(off)
  if (n < 8){
    float r = 0.f;
    for (int i = 0; i < n; ++i){ float x = a[(long)i*st]; float s = x*x; r += s; }
    return r;
  }
  if (n <= 128){
    float x0=a[0],x1=a[st],x2=a[2*st],x3=a[3*st],
          x4=a[4*st],x5=a[5*st],x6=a[6*st],x7=a[7*st];
    float r0=x0*x0, r1=x1*x1, r2=x2*x2, r3=x3*x3,
          r4=x4*x4, r5=x5*x5, r6=x6*x6, r7=x7*x7;
    int i = 8;
    for (; i < n - (n & 7); i += 8){
      float y0=a[(long)(i+0)*st], y1=a[(long)(i+1)*st], y2=a[(long)(i+2)*st], y3=a[(long)(i+3)*st];
      float y4=a[(long)(i+4)*st], y5=a[(long)(i+5)*st], y6=a[(long)(i+6)*st], y7=a[(long)(i+7)*st];
      r0 += y0*y0; r1 += y1*y1; r2 += y2*y2; r3 += y3*y3;
      r4 += y4*y4; r5 += y5*y5; r6 += y6*y6; r7 += y7*y7;
    }
    float res = ((r0 + r1) + (r2 + r3)) + ((r4 + r5) + (r6 + r7));
    for (; i < n; ++i){ float x = a[(long)i*st]; float s = x*x; res += s; }
    return res;
  }
  int n2 = n/2; n2 -= (n2 & 7);
  return np_pw_sq(a, n2, st) + np_pw_sq(a + (long)n2*st, n - n2, st);
}

// ======== phase 0: fsq (np-exact), center row 0, rows 1..3 = 0, zero pcnt
__global__ __launch_bounds__(NTHR)
void k_prep(const float* __restrict__ X, float* __restrict__ C,
            float* __restrict__ fsq, int* __restrict__ pcnt){
  const int blk = blockIdx.x, tid = threadIdx.x;
  int Pf = blk*NTHR + tid;                 // 250*256 = 64000
  int bf = Pf / NPTS, gf = Pf - bf*NPTS;
  int nf = gf / TLEN, tf = gf - nf*TLEN;
  fsq[Pf] = np_pw_sq(X + ((size_t)(bf*NSPK_ + nf)*DIMS)*TLEN + tf, DIMS, TLEN);
  if (blk == 0 && tid < NBATCH) pcnt[tid] = 0;
  if (blk < NBATCH){
    for (int d = tid; d < DIMS; d += NTHR)
      C[blk*KC*DIMS + d] = X[((size_t)(blk*NSPK_)*DIMS + d)*TLEN];
  } else if (blk < 2*NBATCH){
    int bb = blk - NBATCH;
    for (int e = tid; e < 3*DIMS; e += NTHR) C[bb*KC*DIMS + DIMS + e] = 0.f;
  }
}

// ======== init dist: dmin over all 4 rows (zero rows give fsq == reference :i+1 slice)
__global__ __launch_bounds__(NTHR)
void k_dist(const float* __restrict__ X, const float* __restrict__ C,
            const float* __restrict__ fsq, float* __restrict__ dmin){
  const int blk = blockIdx.x, tid = threadIdx.x;
  const int w = tid >> 6, l = tid & 63;
  const int b = blk / BPB;
  const int P = blk*PPB + l;
  const int g = P - b*NPTS;
  const int n = g / TLEN, t = g - n*TLEN;

  __shared__ __align__(16) float cent[DIMS*KC];
  __shared__ float red[4][KC][PPB];
  __shared__ float csq_s[KC];

  const float* Cb = C + b*KC*DIMS;
  #pragma unroll
  for (int j = 0; j < 8; ++j){
    int e = tid*8 + j;
    cent[e] = Cb[(e&3)*DIMS + (e>>2)];
  }
  { const float* ck = Cb + w*DIMS + l*8;
    float s = 0.f;
    #pragma unroll
    for (int j = 0; j < 8; ++j){ float c = ck[j]; s += c*c; }
    #pragma unroll
    for (int o = 32; o; o >>= 1) s += __shfl_xor(s, o, 64);
    if (l == 0) csq_s[w] = s;
  }
  __syncthreads();

  const float* xp = X + (((size_t)(b*NSPK_ + n)*DIMS) + w*128)*TLEN + t;
  const float4* c4p = (const float4*)cent + w*128;
  float a0=0,a1=0,a2=0,a3=0;
  #pragma unroll 8
  for (int dq = 0; dq < 128; ++dq){
    float x = xp[(size_t)dq*TLEN];
    float4 c = c4p[dq];
    a0 += x*c.x; a1 += x*c.y; a2 += x*c.z; a3 += x*c.w;
  }
  red[w][0][l]=a0; red[w][1][l]=a1; red[w][2][l]=a2; red[w][3][l]=a3;
  __syncthreads();
  if (tid < PPB){
    float A0 = red[0][0][l]+red[1][0][l]+red[2][0][l]+red[3][0][l];
    float A1 = red[0][1][l]+red[1][1][l]+red[2][1][l]+red[3][1][l];
    float A2 = red[0][2][l]+red[1][2][l]+red[2][2][l]+red[3][2][l];
    float A3 = red[0][3][l]+red[1][3][l]+red[2][3][l]+red[3][3][l];
    float fs = fsq[P];
    float dm = (fs + csq_s[0]) - 2.f*A0;
    dm = fminf(dm, (fs + csq_s[1]) - 2.f*A1);
    dm = fminf(dm, (fs + csq_s[2]) - 2.f*A2);
    dm = fminf(dm, (fs + csq_s[3]) - 2.f*A3);
    dmin[P] = dm;
  }
}

// ======== selection (np-exact): grid 8, one block per batch; writes center row i
__global__ __launch_bounds__(NTHR)
void k_select(const float* __restrict__ X, float* __restrict__ C,
              const float* __restrict__ dmin, RArg ra, int i){
  const int bs = blockIdx.x, tid = threadIdx.x;
  const int w = tid >> 6, l = tid & 63;
  __shared__ __align__(16) float sbuf[NPTS];   // 32 KB: dmin then q
  __shared__ __align__(16) float pbuf[NPTS];   // 32 KB: fp32-sequential prefix
  __shared__ float fsh[1];
  __shared__ int   ired[4];
  float rT = ra.r[i-1][bs];

  for (int e = tid; e < NPTS; e += NTHR) sbuf[e] = dmin[bs*NPTS + e];
  __syncthreads();
  // total: exact np pairwise tree over all 8000 (identical tree to np.sum)
  if (tid == 0) fsh[0] = np_pw(sbuf, NPTS, 1);
  __syncthreads();
  float tot = fsh[0];
  for (int e = tid; e < NPTS; e += NTHR) sbuf[e] = sbuf[e] / tot;  // IEEE div like np
  __syncthreads();
  // serial fp32 prefix: ONLY the dependent add chain + non-blocking stores
  if (tid == 0){
    #pragma clang fp contract(off)
    float run = 0.f;
    for (int j = 0; j < NPTS; j += 16){
      float vv[16];
      #pragma unroll
      for (int u = 0; u < 16; ++u) vv[u] = sbuf[j + u];
      #pragma unroll
      for (int u = 0; u < 16; ++u){
        run = run + vv[u];            // exact sequential fp32 cumsum
        pbuf[j + u] = run;
      }
    }
  }
  __syncthreads();
  // parallel count of prefix <= r (bitwise-identical comparisons)
  int cnt = 0;
  for (int e = tid; e < NPTS; e += NTHR) cnt += (pbuf[e] <= rT) ? 1 : 0;
  #pragma unroll
  for (int o = 32; o; o >>= 1) cnt += __shfl_xor(cnt, o, 64);
  if (l == 0) ired[w] = cnt;
  __syncthreads();
  int sel = (ired[0] + ired[1] + ired[2] + ired[3]) - 1;
  for (int d = tid; d < DIMS; d += NTHR){
    float v = 0.f;
    if (sel >= 0){
      int ns = sel / TLEN, ts = sel - ns*TLEN;
      v = X[((size_t)(bs*NSPK_ + ns)*DIMS + d)*TLEN + ts];
    }
    C[(bs*KC + i)*DIMS + d] = v;
  }
}

// ======== Lloyd iteration: assignment + partial sums + fused last-block reduce
__global__ __launch_bounds__(NTHR, 2)
void k_iter(const float* __restrict__ X, float* __restrict__ C,
            const float* __restrict__ fsq, float* __restrict__ part,
            int* __restrict__ pnum, int* __restrict__ pcnt){
  const int blk = blockIdx.x, tid = threadIdx.x;
  const int p = tid & 31, dg = tid >> 5;        // point-slot (32), d-group (8x64)
  const int b = blk / BPB;
  const int g0 = (blk - b*BPB)*PPB;             // first point of block within batch

  __shared__ __align__(16) float cent[DIMS*KC];  // 8 KB  [d*4+k]
  __shared__ float tile[DIMS*TS];                // 67.6 KB [d*33 + p]
  __shared__ float red[8][KC][32];               // 4 KB
  __shared__ int   ks[32];
  __shared__ float csq_s[KC];
  __shared__ int   cntk[KC];
  __shared__ int   last_sh;

  // stage centers + csq (mean scale 1/512)
  const float* Cb = C + b*KC*DIMS;
  #pragma unroll
  for (int j = 0; j < 8; ++j){
    int e = tid*8 + j;
    cent[e] = Cb[(e&3)*DIMS + (e>>2)];
  }
  { const int w = tid >> 6, l = tid & 63;
    const float* ck = Cb + w*DIMS + l*8;
    float s = 0.f;
    #pragma unroll
    for (int j = 0; j < 8; ++j){ float c = ck[j]; s += c*c; }
    #pragma unroll
    for (int o = 32; o; o >>= 1) s += __shfl_xor(s, o, 64);
    if (l == 0) csq_s[w] = s * (1.f/512.f);
  }
  if (tid < KC) cntk[tid] = 0;
  __syncthreads();

  float s00=0,s01=0,s02=0,s03=0, s10=0,s11=0,s12=0,s13=0;
  const int d0 = tid, d1 = tid + 256;

  for (int h = 0; h < 2; ++h){
    const int g = g0 + h*32 + p;
    const int n = g / TLEN, t = g - n*TLEN;
    const float* xp = X + (((size_t)(b*NSPK_ + n)*DIMS) + dg*64)*TLEN + t;
    float a0=0,a1=0,a2=0,a3=0;
    #pragma unroll 8
    for (int dd = 0; dd < 64; ++dd){
      float x = xp[(size_t)dd*TLEN];
      int d = dg*64 + dd;
      tile[d*TS + p] = x;
      float4 c = ((const float4*)cent)[d];
      a0 += x*c.x; a1 += x*c.y; a2 += x*c.z; a3 += x*c.w;
    }
    red[dg][0][p]=a0; red[dg][1][p]=a1; red[dg][2][p]=a2; red[dg][3][p]=a3;
    __syncthreads();
    if (tid < 32){
      float A0=0,A1=0,A2=0,A3=0;
      #pragma unroll
      for (int q = 0; q < 8; ++q){
        A0 += red[q][0][tid]; A1 += red[q][1][tid];
        A2 += red[q][2][tid]; A3 += red[q][3][tid];
      }
      float xs = fsq[b*NPTS + g0 + h*32 + tid] * (1.f/512.f);
      float e0 = (xs + csq_s[0]) - 2.f*(A0*(1.f/512.f));
      float e1 = (xs + csq_s[1]) - 2.f*(A1*(1.f/512.f));
      float e2 = (xs + csq_s[2]) - 2.f*(A2*(1.f/512.f));
      float e3 = (xs + csq_s[3]) - 2.f*(A3*(1.f/512.f));
      int bi = 0; float bv = e0;            // first-min == np.argmin
      if (e1 < bv){ bv = e1; bi = 1; }
      if (e2 < bv){ bv = e2; bi = 2; }
      if (e3 < bv){ bv = e3; bi = 3; }
      ks[tid] = bi;
      unsigned long long m0 = __ballot(bi==0), m1 = __ballot(bi==1);
      unsigned long long m2 = __ballot(bi==2), m3 = __ballot(bi==3);
      if (tid == 0){
        cntk[0] += __popcll(m0); cntk[1] += __popcll(m1);
        cntk[2] += __popcll(m2); cntk[3] += __popcll(m3);
      }
    }
    __syncthreads();
    #pragma unroll 4
    for (int p2 = 0; p2 < 32; ++p2){
      int kk = __builtin_amdgcn_readfirstlane(ks[p2]);   // wave-uniform scalar
      float x0 = tile[d0*TS + p2];
      float x1 = tile[d1*TS + p2];
      if (kk == 0){ s00 += x0; s10 += x1; }
      else if (kk == 1){ s01 += x0; s11 += x1; }
      else if (kk == 2){ s02 += x0; s12 += x1; }
      else { s03 += x0; s13 += x1; }
    }
    __syncthreads();   // tile reused next half
  }

  if (tid < KC) pnum[blk*4 + tid] = cntk[tid];
  part[((size_t)blk*KC + 0)*DIMS + d0] = s00;
  part[((size_t)blk*KC + 1)*DIMS + d0] = s01;
  part[((size_t)blk*KC + 2)*DIMS + d0] = s02;
  part[((size_t)blk*KC + 3)*DIMS + d0] = s03;
  part[((size_t)blk*KC + 0)*DIMS + d1] = s10;
  part[((size_t)blk*KC + 1)*DIMS + d1] = s11;
  part[((size_t)blk*KC + 2)*DIMS + d1] = s12;
  part[((size_t)blk*KC + 3)*DIMS + d1] = s13;

  // ---- last block of this batch reduces partials -> centers
  __threadfence();                     // release this thread's stores (device scope)
  __syncthreads();                     // all threads' fences done before the atomic
  if (tid == 0) last_sh = (atomicAdd(&pcnt[b], 1) == BPB-1);
  __syncthreads();
  if (!last_sh) return;
  __threadfence();                     // acquire: see other blocks' partials

  const int k = tid >> 6, l = tid & 63;
  // counts for cluster k (wave w <-> k), fixed-order irrelevant (ints, exact)
  int v = pnum[(b*BPB + l)*4 + k];
  if (l < BPB - 64) v += pnum[(b*BPB + 64 + l)*4 + k];
  #pragma unroll
  for (int o = 32; o; o >>= 1) v += __shfl_xor(v, o, 64);
  float den = (float)v + 1e-8f;
  // sums: thread handles 8 d's for cluster k, j-order 0..124 (deterministic)
  float4 s0 = {0,0,0,0}, s1 = {0,0,0,0};
  const float* pb = part + ((size_t)(b*BPB)*KC + k)*DIMS + l*8;
  #pragma unroll 5
  for (int j = 0; j < BPB; ++j){
    const float4* q = (const float4*)(pb + (size_t)j*KC*DIMS);
    float4 a = q[0], c = q[1];
    s0.x += a.x; s0.y += a.y; s0.z += a.z; s0.w += a.w;
    s1.x += c.x; s1.y += c.y; s1.z += c.z; s1.w += c.w;
  }
  float4 o0, o1;
  o0.x = s0.x/den; o0.y = s0.y/den; o0.z = s0.z/den; o0.w = s0.w/den;
  o1.x = s1.x/den; o1.y = s1.y/den; o1.z = s1.z/den; o1.w = s1.w/den;
  float4* cp = (float4*)(C + (size_t)(b*KC + k)*DIMS + l*8);
  cp[0] = o0; cp[1] = o1;
  if (tid == 0) atomicExch(&pcnt[b], 0);   // reset for next launch (stream-ordered)
}

// ======================= host: threefry2x32 (JAX-compatible) =======================
static inline uint32_t rotl_(uint32_t x, int r){ return (x << r) | (x >> (32 - r)); }
static void tf2x32(uint32_t k0, uint32_t k1, uint32_t x0, uint32_t x1,
                   uint32_t* o0, uint32_t* o1){
  static const int R0[4] = {13,15,26,6}, R1[4] = {17,29,16,24};
  uint32_t ks[3] = { k0, k1, k0 ^ k1 ^ 0x1BD11BDAu };
  x0 += ks[0]; x1 += ks[1];
  for (int g = 0; g < 5; ++g){
    const int* rot = (g & 1) ? R1 : R0;
    for (int r = 0; r < 4; ++r){ x0 += x1; x1 = rotl_(x1, rot[r]); x1 ^= x0; }
    x0 += ks[(g+1)%3];
    x1 += ks[(g+2)%3] + (uint32_t)(g+1);
  }
  *o0 = x0; *o1 = x1;
}
static float tf_uniform_bits(uint32_t bits){
  uint32_t u = (bits >> 9) | 0x3f800000u;
  float f; memcpy(&f, &u, 4);
  return f - 1.0f;
}

extern "C" void kernel_launch(void* const* d_in, const int* in_sizes, int n_in,
                              void* d_out, int out_size, void* d_ws, size_t ws_size,
                              hipStream_t stream) {
  (void)in_sizes; (void)n_in; (void)out_size; (void)ws_size;
  const float* X = (const float*)d_in[0];
  float* centers = (float*)d_out;                 // (8,4,512)

  char* w = (char*)d_ws;
  float* fsq  = (float*)w;  w += (size_t)NBATCH*NPTS*4;            // 256 KB
  float* dmin = (float*)w;  w += (size_t)NBATCH*NPTS*4;            // 256 KB
  float* part = (float*)w;  w += (size_t)NBLK*KC*DIMS*4;           // 8.2 MB
  int*   pnum = (int*)w;    w += (size_t)NBLK*KC*4;                // 16 KB
  int*   pcnt = (int*)w;    w += 256;

  RArg ra;
  uint32_t k0 = 0u, k1 = 1u;
  for (int i = 0; i < 3; ++i){
#if THREEFRY_PARTITIONABLE
    uint32_t nk0, nk1, s0, s1;
    tf2x32(k0, k1, 0u, 0u, &nk0, &nk1);
    tf2x32(k0, k1, 0u, 1u, &s0, &s1);
    k0 = nk0; k1 = nk1;
    for (int bq = 0; bq < NBATCH; ++bq){
      uint32_t b1v, b2v; tf2x32(s0, s1, 0u, (uint32_t)bq, &b1v, &b2v);
      ra.r[i][bq] = tf_uniform_bits(b1v ^ b2v);
    }
#else
    uint32_t a0, b0, a1, b1;
    tf2x32(k0, k1, 0u, 2u, &a0, &b0);
    tf2x32(k0, k1, 1u, 3u, &a1, &b1);
    uint32_t s0 = b0, s1 = b1;
    k0 = a0; k1 = a1;
    uint32_t bits[8];
    for (int j = 0; j < 4; ++j){
      uint32_t c, d2; tf2x32(s0, s1, (uint32_t)j, (uint32_t)(j+4), &c, &d2);
      bits[j] = c; bits[j+4] = d2;
    }
    for (int bq = 0; bq < NBATCH; ++bq) ra.r[i][bq] = tf_uniform_bits(bits[bq]);
#endif
  }

  hipLaunchKernelGGL(k_prep, dim3(250), dim3(NTHR), 0, stream, X, centers, fsq, pcnt);
  for (int i = 1; i < KC; ++i){
    hipLaunchKernelGGL(k_dist, dim3(NBLK), dim3(NTHR), 0, stream, X, centers, fsq, dmin);
    hipLaunchKernelGGL(k_select, dim3(NBATCH), dim3(NTHR), 0, stream, X, centers, dmin, ra, i);
  }
  for (int it = 0; it < MAXIT; ++it){
    hipLaunchKernelGGL(k_iter, dim3(NBLK), dim3(NTHR), 0, stream, X, centers, fsq,
                       part, pnum, pcnt);
  }
}

// Round 7
// 5976.416 us; speedup vs baseline: 2.9077x; 2.9077x over previous
//
#include <hip/hip_runtime.h>
#include <stdint.h>
#include <string.h>

#define NBATCH 8
#define NSPK_  4
#define DIMS   512
#define TLEN   2000
#define KC     4
#define NPTS   8000            // points per batch
#define NBLK   1000            // Lloyd / dist grid
#define NTHR   256
#define PPB    64              // points per block
#define BPB    125             // blocks per batch
#define MAXIT  100
#define TS     33              // k_iter LDS tile row stride (d-major)

#define THREEFRY_PARTITIONABLE 1

struct RArg { float r[3][NBATCH]; };

// ---- exact replica of numpy pairwise_sum (umath loops), stride in elements ----
__device__ float np_pw(const float* a, int n, int st){
  #pragma clang fp contract(off)
  if (n < 8){
    float r = 0.f;
    for (int i = 0; i < n; ++i) r += a[(long)i*st];
    return r;
  }
  if (n <= 128){
    float r0=a[0], r1=a[st], r2=a[2*st], r3=a[3*st],
          r4=a[4*st], r5=a[5*st], r6=a[6*st], r7=a[7*st];
    int i = 8;
    for (; i < n - (n & 7); i += 8){
      r0 += a[(long)(i+0)*st]; r1 += a[(long)(i+1)*st];
      r2 += a[(long)(i+2)*st]; r3 += a[(long)(i+3)*st];
      r4 += a[(long)(i+4)*st]; r5 += a[(long)(i+5)*st];
      r6 += a[(long)(i+6)*st]; r7 += a[(long)(i+7)*st];
    }
    float res = ((r0 + r1) + (r2 + r3)) + ((r4 + r5) + (r6 + r7));
    for (; i < n; ++i) res += a[(long)i*st];
    return res;
  }
  int n2 = n/2; n2 -= (n2 & 7);
  return np_pw(a, n2, st) + np_pw(a + (long)n2*st, n - n2, st);
}
__device__ float np_pw_sq(const float* a, int n, int st){
  #pragma clang fp contract(off)
  if (n < 8){
    float r = 0.f;
    for (int i = 0; i < n; ++i){ float x = a[(long)i*st]; float s = x*x; r += s; }
    return r;
  }
  if (n <= 128){
    float x0=a[0],x1=a[st],x2=a[2*st],x3=a[3*st],
          x4=a[4*st],x5=a[5*st],x6=a[6*st],x7=a[7*st];
    float r0=x0*x0, r1=x1*x1, r2=x2*x2, r3=x3*x3,
          r4=x4*x4, r5=x5*x5, r6=x6*x6, r7=x7*x7;
    int i = 8;
    for (; i < n - (n & 7); i += 8){
      float y0=a[(long)(i+0)*st], y1=a[(long)(i+1)*st], y2=a[(long)(i+2)*st], y3=a[(long)(i+3)*st];
      float y4=a[(long)(i+4)*st], y5=a[(long)(i+5)*st], y6=a[(long)(i+6)*st], y7=a[(long)(i+7)*st];
      r0 += y0*y0; r1 += y1*y1; r2 += y2*y2; r3 += y3*y3;
      r4 += y4*y4; r5 += y5*y5; r6 += y6*y6; r7 += y7*y7;
    }
    float res = ((r0 + r1) + (r2 + r3)) + ((r4 + r5) + (r6 + r7));
    for (; i < n; ++i){ float x = a[(long)i*st]; float s = x*x; res += s; }
    return res;
  }
  int n2 = n/2; n2 -= (n2 & 7);
  return np_pw_sq(a, n2, st) + np_pw_sq(a + (long)n2*st, n - n2, st);
}

// ======== phase 0: fsq (np-exact), center row 0 = feature[:,0,:,0], rows 1..3 = 0
__global__ __launch_bounds__(NTHR)
void k_prep(const float* __restrict__ X, float* __restrict__ C, float* __restrict__ fsq){
  const int blk = blockIdx.x, tid = threadIdx.x;
  int Pf = blk*NTHR + tid;                 // 250*256 = 64000
  int bf = Pf / NPTS, gf = Pf - bf*NPTS;
  int nf = gf / TLEN, tf = gf - nf*TLEN;
  fsq[Pf] = np_pw_sq(X + ((size_t)(bf*NSPK_ + nf)*DIMS)*TLEN + tf, DIMS, TLEN);
  if (blk < NBATCH){
    for (int d = tid; d < DIMS; d += NTHR)
      C[blk*KC*DIMS + d] = X[((size_t)(blk*NSPK_)*DIMS + d)*TLEN];
  } else if (blk < 2*NBATCH){
    int bb = blk - NBATCH;
    for (int e = tid; e < 3*DIMS; e += NTHR) C[bb*KC*DIMS + DIMS + e] = 0.f;
  }
}

// ======== init dist: dmin over all 4 rows (zero rows give fsq == reference :i+1 slice)
__global__ __launch_bounds__(NTHR)
void k_dist(const float* __restrict__ X, const float* __restrict__ C,
            const float* __restrict__ fsq, float* __restrict__ dmin){
  const int blk = blockIdx.x, tid = threadIdx.x;
  const int w = tid >> 6, l = tid & 63;
  const int b = blk / BPB;
  const int P = blk*PPB + l;
  const int g = P - b*NPTS;
  const int n = g / TLEN, t = g - n*TLEN;

  __shared__ __align__(16) float cent[DIMS*KC];
  __shared__ float red[4][KC][PPB];
  __shared__ float csq_s[KC];

  const float* Cb = C + b*KC*DIMS;
  #pragma unroll
  for (int j = 0; j < 8; ++j){
    int e = tid*8 + j;
    cent[e] = Cb[(e&3)*DIMS + (e>>2)];
  }
  { const float* ck = Cb + w*DIMS + l*8;
    float s = 0.f;
    #pragma unroll
    for (int j = 0; j < 8; ++j){ float c = ck[j]; s += c*c; }
    #pragma unroll
    for (int o = 32; o; o >>= 1) s += __shfl_xor(s, o, 64);
    if (l == 0) csq_s[w] = s;
  }
  __syncthreads();

  const float* xp = X + (((size_t)(b*NSPK_ + n)*DIMS) + w*128)*TLEN + t;
  const float4* c4p = (const float4*)cent + w*128;
  float a0=0,a1=0,a2=0,a3=0;
  #pragma unroll 8
  for (int dq = 0; dq < 128; ++dq){
    float x = xp[(size_t)dq*TLEN];
    float4 c = c4p[dq];
    a0 += x*c.x; a1 += x*c.y; a2 += x*c.z; a3 += x*c.w;
  }
  red[w][0][l]=a0; red[w][1][l]=a1; red[w][2][l]=a2; red[w][3][l]=a3;
  __syncthreads();
  if (tid < PPB){
    float A0 = red[0][0][l]+red[1][0][l]+red[2][0][l]+red[3][0][l];
    float A1 = red[0][1][l]+red[1][1][l]+red[2][1][l]+red[3][1][l];
    float A2 = red[0][2][l]+red[1][2][l]+red[2][2][l]+red[3][2][l];
    float A3 = red[0][3][l]+red[1][3][l]+red[2][3][l]+red[3][3][l];
    float fs = fsq[P];
    float dm = (fs + csq_s[0]) - 2.f*A0;
    dm = fminf(dm, (fs + csq_s[1]) - 2.f*A1);
    dm = fminf(dm, (fs + csq_s[2]) - 2.f*A2);
    dm = fminf(dm, (fs + csq_s[3]) - 2.f*A3);
    dmin[P] = dm;
  }
}

// ======== selection (np-exact): grid 8, one block per batch; writes center row i
__global__ __launch_bounds__(NTHR)
void k_select(const float* __restrict__ X, float* __restrict__ C,
              const float* __restrict__ dmin, RArg ra, int i){
  const int bs = blockIdx.x, tid = threadIdx.x;
  const int w = tid >> 6, l = tid & 63;
  __shared__ __align__(16) float sbuf[NPTS];   // 32 KB
  __shared__ __align__(16) float pbuf[NPTS];   // 32 KB
  __shared__ float fsh[1];
  __shared__ int   ired[4];
  float rT = ra.r[i-1][bs];

  for (int e = tid; e < NPTS; e += NTHR) sbuf[e] = dmin[bs*NPTS + e];
  __syncthreads();
  // np.sum(8000): exact pairwise tree = 64 leaves (8 per 1000-chunk, numpy's
  // n2-=n2&7 split) combined by a perfect binary tree; xor-butterfly lane 0
  // reproduces the exact left-first pairing at every level.
  if (w == 0){
    const int chunk = l >> 3, idx = l & 7;
    const int offs[8] = {0,120,248,368,496,616,744,872};
    int off = chunk*1000 + offs[idx];
    int len = (idx==0 || idx==2 || idx==4) ? 120 : 128;
    float v = np_pw(sbuf + off, len, 1);
    #pragma unroll
    for (int o = 1; o < 64; o <<= 1) v = v + __shfl_xor(v, o, 64);
    if (l == 0) fsh[0] = v;
  }
  __syncthreads();
  float tot = fsh[0];
  for (int e = tid; e < NPTS; e += NTHR) sbuf[e] = sbuf[e] / tot;  // IEEE div like np
  __syncthreads();
  // serial fp32 prefix: software-pipelined (load batch j+1 during adds of batch j)
  if (tid == 0){
    #pragma clang fp contract(off)
    float b0[32], b1[32];
    #pragma unroll
    for (int u = 0; u < 32; ++u) b0[u] = sbuf[u];
    float run = 0.f;
    for (int j = 0; j < NPTS; j += 64){
      #pragma unroll
      for (int u = 0; u < 32; ++u) b1[u] = sbuf[j + 32 + u];
      #pragma unroll
      for (int u = 0; u < 32; ++u){ run = run + b0[u]; pbuf[j + u] = run; }
      if (j + 64 < NPTS){
        #pragma unroll
        for (int u = 0; u < 32; ++u) b0[u] = sbuf[j + 64 + u];
      }
      #pragma unroll
      for (int u = 0; u < 32; ++u){ run = run + b1[u]; pbuf[j + 32 + u] = run; }
    }
  }
  __syncthreads();
  // parallel count of prefix <= r (bitwise-identical comparisons)
  int cnt = 0;
  for (int e = tid; e < NPTS; e += NTHR) cnt += (pbuf[e] <= rT) ? 1 : 0;
  #pragma unroll
  for (int o = 32; o; o >>= 1) cnt += __shfl_xor(cnt, o, 64);
  if (l == 0) ired[w] = cnt;
  __syncthreads();
  int sel = (ired[0] + ired[1] + ired[2] + ired[3]) - 1;
  for (int d = tid; d < DIMS; d += NTHR){
    float v = 0.f;
    if (sel >= 0){
      int ns = sel / TLEN, ts = sel - ns*TLEN;
      v = X[((size_t)(bs*NSPK_ + ns)*DIMS + d)*TLEN + ts];
    }
    C[(bs*KC + i)*DIMS + d] = v;
  }
}

// ======== Lloyd iteration: float4-t loads, single X read, assignment + partial sums
// thread = (dgg = tid>>3 in 0..31, pq = tid&7); d = dd*32 + dgg; points pq*4..pq*4+3
__global__ __launch_bounds__(NTHR, 2)
void k_iter(const float* __restrict__ X, const float* __restrict__ C,
            const float* __restrict__ fsq, float* __restrict__ part,
            int* __restrict__ pnum){
  const int blk = blockIdx.x, tid = threadIdx.x;
  const int w = tid >> 6;
  const int pq = tid & 7;
  const int dgg = tid >> 3;                 // 0..31
  const int b = blk / BPB;
  const int g0 = (blk - b*BPB)*PPB;

  __shared__ __align__(16) float cent[DIMS*KC];  // 8 KB  [d*4+k]
  __shared__ float tile[DIMS*TS];                // 67.6 KB [d*33 + p]
  __shared__ __align__(16) float red2[4][8][16]; // 2 KB [wave][pq][j*4+k]
  __shared__ int   ks[32];
  __shared__ float csq_s[KC];
  __shared__ int   cntk[KC];

  // stage centers (d-major float4 over k) + csq (mean scale 1/512)
  const float* Cb = C + b*KC*DIMS;
  #pragma unroll
  for (int j = 0; j < 8; ++j){
    int e = tid*8 + j;
    cent[e] = Cb[(e&3)*DIMS + (e>>2)];
  }
  { const int l = tid & 63;
    const float* ck = Cb + w*DIMS + l*8;
    float s = 0.f;
    #pragma unroll
    for (int j = 0; j < 8; ++j){ float c = ck[j]; s += c*c; }
    #pragma unroll
    for (int o = 32; o; o >>= 1) s += __shfl_xor(s, o, 64);
    if (l == 0) csq_s[w] = s * (1.f/512.f);
  }
  if (tid < KC) cntk[tid] = 0;
  __syncthreads();

  // preload this thread's 16 center quads: d = dd*32 + dgg (conflict-free b128)
  float4 cr[16];
  #pragma unroll
  for (int dd = 0; dd < 16; ++dd) cr[dd] = ((const float4*)cent)[dd*32 + dgg];

  float s00=0,s01=0,s02=0,s03=0, s10=0,s11=0,s12=0,s13=0;
  const int d0 = tid, d1 = tid + 256;

  for (int h = 0; h < 2; ++h){
    const int gp = g0 + h*32 + pq*4;          // 2000%4==0 -> quad never straddles n
    const int n = gp / TLEN, t = gp - n*TLEN;
    const float* xr = X + ((size_t)(b*NSPK_ + n)*DIMS + dgg)*TLEN + t;
    float4 a0 = {0,0,0,0}, a1 = {0,0,0,0}, a2 = {0,0,0,0}, a3 = {0,0,0,0};
    #pragma unroll
    for (int dd = 0; dd < 16; ++dd){
      float4 x4 = *(const float4*)(xr + (size_t)dd*32*TLEN);
      int dw = (dd*32 + dgg)*TS + pq*4;
      tile[dw+0] = x4.x; tile[dw+1] = x4.y; tile[dw+2] = x4.z; tile[dw+3] = x4.w;
      float4 c = cr[dd];
      a0.x += x4.x*c.x; a0.y += x4.x*c.y; a0.z += x4.x*c.z; a0.w += x4.x*c.w;
      a1.x += x4.y*c.x; a1.y += x4.y*c.y; a1.z += x4.y*c.z; a1.w += x4.y*c.w;
      a2.x += x4.z*c.x; a2.y += x4.z*c.y; a2.z += x4.z*c.z; a2.w += x4.z*c.w;
      a3.x += x4.w*c.x; a3.y += x4.w*c.y; a3.z += x4.w*c.z; a3.w += x4.w*c.w;
    }
    // in-wave reduce over the 8 dgg-lanes sharing this pq (fixed order)
    #pragma unroll
    for (int o = 8; o <= 32; o <<= 1){
      a0.x += __shfl_xor(a0.x,o,64); a0.y += __shfl_xor(a0.y,o,64);
      a0.z += __shfl_xor(a0.z,o,64); a0.w += __shfl_xor(a0.w,o,64);
      a1.x += __shfl_xor(a1.x,o,64); a1.y += __shfl_xor(a1.y,o,64);
      a1.z += __shfl_xor(a1.z,o,64); a1.w += __shfl_xor(a1.w,o,64);
      a2.x += __shfl_xor(a2.x,o,64); a2.y += __shfl_xor(a2.y,o,64);
      a2.z += __shfl_xor(a2.z,o,64); a2.w += __shfl_xor(a2.w,o,64);
      a3.x += __shfl_xor(a3.x,o,64); a3.y += __shfl_xor(a3.y,o,64);
      a3.z += __shfl_xor(a3.z,o,64); a3.w += __shfl_xor(a3.w,o,64);
    }
    if ((tid & 56) == 0){                      // one lane per (wave, pq)
      float4* r4 = (float4*)&red2[w][pq][0];
      r4[0] = a0; r4[1] = a1; r4[2] = a2; r4[3] = a3;
    }
    __syncthreads();
    if (tid < 32){
      int p = tid, pqq = p >> 2, j = p & 3;
      float4 A = {0,0,0,0};
      #pragma unroll
      for (int q = 0; q < 4; ++q){
        float4 v = ((const float4*)&red2[q][pqq][0])[j];
        A.x += v.x; A.y += v.y; A.z += v.z; A.w += v.w;
      }
      float xs = fsq[b*NPTS + g0 + h*32 + p] * (1.f/512.f);
      float e0 = (xs + csq_s[0]) - 2.f*(A.x*(1.f/512.f));
      float e1 = (xs + csq_s[1]) - 2.f*(A.y*(1.f/512.f));
      float e2 = (xs + csq_s[2]) - 2.f*(A.z*(1.f/512.f));
      float e3 = (xs + csq_s[3]) - 2.f*(A.w*(1.f/512.f));
      int bi = 0; float bv = e0;            // first-min == np.argmin
      if (e1 < bv){ bv = e1; bi = 1; }
      if (e2 < bv){ bv = e2; bi = 2; }
      if (e3 < bv){ bv = e3; bi = 3; }
      ks[p] = bi;
      unsigned long long m0 = __ballot(bi==0), m1 = __ballot(bi==1);
      unsigned long long m2 = __ballot(bi==2), m3 = __ballot(bi==3);
      if (p == 0){
        cntk[0] += __popcll(m0); cntk[1] += __popcll(m1);
        cntk[2] += __popcll(m2); cntk[3] += __popcll(m3);
      }
    }
    __syncthreads();
    // cluster sums from tile (thread <-> d, wave-uniform k), stride-33 conflict-free
    #pragma unroll 4
    for (int p2 = 0; p2 < 32; ++p2){
      int kk = __builtin_amdgcn_readfirstlane(ks[p2]);
      float x0 = tile[d0*TS + p2];
      float x1 = tile[d1*TS + p2];
      if (kk == 0){ s00 += x0; s10 += x1; }
      else if (kk == 1){ s01 += x0; s11 += x1; }
      else if (kk == 2){ s02 += x0; s12 += x1; }
      else { s03 += x0; s13 += x1; }
    }
    __syncthreads();   // tile/red2/ks reused next half
  }

  if (tid < KC) pnum[blk*4 + tid] = cntk[tid];
  part[((size_t)blk*KC + 0)*DIMS + d0] = s00;
  part[((size_t)blk*KC + 1)*DIMS + d0] = s01;
  part[((size_t)blk*KC + 2)*DIMS + d0] = s02;
  part[((size_t)blk*KC + 3)*DIMS + d0] = s03;
  part[((size_t)blk*KC + 0)*DIMS + d1] = s10;
  part[((size_t)blk*KC + 1)*DIMS + d1] = s11;
  part[((size_t)blk*KC + 2)*DIMS + d1] = s12;
  part[((size_t)blk*KC + 3)*DIMS + d1] = s13;
}

// ======== reduce partials -> centers. grid 256: blk = (bb*4+k)*8 + seg(64 d's)
__global__ __launch_bounds__(NTHR)
void k_reduce(const float* __restrict__ part, const int* __restrict__ pnum,
              float* __restrict__ C){
  const int blk = blockIdx.x, tid = threadIdx.x;
  const int seg = blk & 7, bk = blk >> 3;
  const int bb = bk >> 2, k = bk & 3;
  const int w = tid >> 6, l = tid & 63;
  __shared__ float red[4][64];
  __shared__ int ns[4];

  int v = 0;
  if (tid < BPB) v = pnum[(bb*BPB + tid)*4 + k];
  #pragma unroll
  for (int o = 32; o; o >>= 1) v += __shfl_xor(v, o, 64);
  if (l == 0) ns[w] = v;
  __syncthreads();
  float den = (float)(ns[0]+ns[1]+ns[2]+ns[3]) + 1e-8f;

  int jb = (BPB*w) >> 2, je = (BPB*(w+1)) >> 2;   // fixed quarters of 125
  float s = 0.f;
  for (int j = jb; j < je; ++j)
    s += part[((size_t)(bb*BPB + j)*KC + k)*DIMS + seg*64 + l];
  red[w][l] = s;
  __syncthreads();
  if (tid < 64){
    float tsum = red[0][l] + red[1][l] + red[2][l] + red[3][l];
    C[bk*DIMS + seg*64 + l] = tsum / den;
  }
}

// ======================= host: threefry2x32 (JAX-compatible) =======================
static inline uint32_t rotl_(uint32_t x, int r){ return (x << r) | (x >> (32 - r)); }
static void tf2x32(uint32_t k0, uint32_t k1, uint32_t x0, uint32_t x1,
                   uint32_t* o0, uint32_t* o1){
  static const int R0[4] = {13,15,26,6}, R1[4] = {17,29,16,24};
  uint32_t ks[3] = { k0, k1, k0 ^ k1 ^ 0x1BD11BDAu };
  x0 += ks[0]; x1 += ks[1];
  for (int g = 0; g < 5; ++g){
    const int* rot = (g & 1) ? R1 : R0;
    for (int r = 0; r < 4; ++r){ x0 += x1; x1 = rotl_(x1, rot[r]); x1 ^= x0; }
    x0 += ks[(g+1)%3];
    x1 += ks[(g+2)%3] + (uint32_t)(g+1);
  }
  *o0 = x0; *o1 = x1;
}
static float tf_uniform_bits(uint32_t bits){
  uint32_t u = (bits >> 9) | 0x3f800000u;
  float f; memcpy(&f, &u, 4);
  return f - 1.0f;
}

extern "C" void kernel_launch(void* const* d_in, const int* in_sizes, int n_in,
                              void* d_out, int out_size, void* d_ws, size_t ws_size,
                              hipStream_t stream) {
  (void)in_sizes; (void)n_in; (void)out_size; (void)ws_size;
  const float* X = (const float*)d_in[0];
  float* centers = (float*)d_out;                 // (8,4,512)

  char* w = (char*)d_ws;
  float* fsq  = (float*)w;  w += (size_t)NBATCH*NPTS*4;            // 256 KB
  float* dmin = (float*)w;  w += (size_t)NBATCH*NPTS*4;            // 256 KB
  float* part = (float*)w;  w += (size_t)NBLK*KC*DIMS*4;           // 8.2 MB
  int*   pnum = (int*)w;    w += (size_t)NBLK*KC*4;                // 16 KB

  RArg ra;
  uint32_t k0 = 0u, k1 = 1u;
  for (int i = 0; i < 3; ++i){
#if THREEFRY_PARTITIONABLE
    uint32_t nk0, nk1, s0, s1;
    tf2x32(k0, k1, 0u, 0u, &nk0, &nk1);
    tf2x32(k0, k1, 0u, 1u, &s0, &s1);
    k0 = nk0; k1 = nk1;
    for (int bq = 0; bq < NBATCH; ++bq){
      uint32_t b1v, b2v; tf2x32(s0, s1, 0u, (uint32_t)bq, &b1v, &b2v);
      ra.r[i][bq] = tf_uniform_bits(b1v ^ b2v);
    }
#else
    uint32_t a0, b0, a1, b1;
    tf2x32(k0, k1, 0u, 2u, &a0, &b0);
    tf2x32(k0, k1, 1u, 3u, &a1, &b1);
    uint32_t s0 = b0, s1 = b1;
    k0 = a0; k1 = a1;
    uint32_t bits[8];
    for (int j = 0; j < 4; ++j){
      uint32_t c, d2; tf2x32(s0, s1, (uint32_t)j, (uint32_t)(j+4), &c, &d2);
      bits[j] = c; bits[j+4] = d2;
    }
    for (int bq = 0; bq < NBATCH; ++bq) ra.r[i][bq] = tf_uniform_bits(bits[bq]);
#endif
  }

  hipLaunchKernelGGL(k_prep, dim3(250), dim3(NTHR), 0, stream, X, centers, fsq);
  for (int i = 1; i < KC; ++i){
    hipLaunchKernelGGL(k_dist, dim3(NBLK), dim3(NTHR), 0, stream, X, centers, fsq, dmin);
    hipLaunchKernelGGL(k_select, dim3(NBATCH), dim3(NTHR), 0, stream, X, centers, dmin, ra, i);
  }
  for (int it = 0; it < MAXIT; ++it){
    hipLaunchKernelGGL(k_iter, dim3(NBLK), dim3(NTHR), 0, stream, X, centers, fsq, part, pnum);
    hipLaunchKernelGGL(k_reduce, dim3(256), dim3(NTHR), 0, stream, part, pnum, centers);
  }
}

// Round 8
// 5721.642 us; speedup vs baseline: 3.0371x; 1.0445x over previous
//
#include <hip/hip_runtime.h>
#include <stdint.h>
#include <string.h>

#define NBATCH 8
#define NSPK_  4
#define DIMS   512
#define TLEN   2000
#define KC     4
#define NPTS   8000            // points per batch
#define NBLK   1000            // Lloyd / dist / prep grid
#define NTHR   256
#define PPB    64              // points per block
#define BPB    125             // blocks per batch
#define MAXIT  100
#define TS2    17              // k_iter LDS tile row stride (16 pts + 1 pad)

#define THREEFRY_PARTITIONABLE 1

struct RArg { float r[3][NBATCH]; };

// ---- exact replica of numpy pairwise_sum (umath loops), stride in elements ----
__device__ float np_pw(const float* a, int n, int st){
  #pragma clang fp contract(off)
  if (n < 8){
    float r = 0.f;
    for (int i = 0; i < n; ++i) r += a[(long)i*st];
    return r;
  }
  if (n <= 128){
    float r0=a[0], r1=a[st], r2=a[2*st], r3=a[3*st],
          r4=a[4*st], r5=a[5*st], r6=a[6*st], r7=a[7*st];
    int i = 8;
    for (; i < n - (n & 7); i += 8){
      r0 += a[(long)(i+0)*st]; r1 += a[(long)(i+1)*st];
      r2 += a[(long)(i+2)*st]; r3 += a[(long)(i+3)*st];
      r4 += a[(long)(i+4)*st]; r5 += a[(long)(i+5)*st];
      r6 += a[(long)(i+6)*st]; r7 += a[(long)(i+7)*st];
    }
    float res = ((r0 + r1) + (r2 + r3)) + ((r4 + r5) + (r6 + r7));
    for (; i < n; ++i) res += a[(long)i*st];
    return res;
  }
  int n2 = n/2; n2 -= (n2 & 7);
  return np_pw(a, n2, st) + np_pw(a + (long)n2*st, n - n2, st);
}
__device__ float np_pw_sq(const float* a, int n, int st){
  #pragma clang fp contract(off)
  if (n < 8){
    float r = 0.f;
    for (int i = 0; i < n; ++i){ float x = a[(long)i*st]; float s = x*x; r += s; }
    return r;
  }
  if (n <= 128){
    float x0=a[0],x1=a[st],x2=a[2*st],x3=a[3*st],
          x4=a[4*st],x5=a[5*st],x6=a[6*st],x7=a[7*st];
    float r0=x0*x0, r1=x1*x1, r2=x2*x2, r3=x3*x3,
          r4=x4*x4, r5=x5*x5, r6=x6*x6, r7=x7*x7;
    int i = 8;
    for (; i < n - (n & 7); i += 8){
      float y0=a[(long)(i+0)*st], y1=a[(long)(i+1)*st], y2=a[(long)(i+2)*st], y3=a[(long)(i+3)*st];
      float y4=a[(long)(i+4)*st], y5=a[(long)(i+5)*st], y6=a[(long)(i+6)*st], y7=a[(long)(i+7)*st];
      r0 += y0*y0; r1 += y1*y1; r2 += y2*y2; r3 += y3*y3;
      r4 += y4*y4; r5 += y5*y5; r6 += y6*y6; r7 += y7*y7;
    }
    float res = ((r0 + r1) + (r2 + r3)) + ((r4 + r5) + (r6 + r7));
    for (; i < n; ++i){ float x = a[(long)i*st]; float s = x*x; res += s; }
    return res;
  }
  int n2 = n/2; n2 -= (n2 & 7);
  return np_pw_sq(a, n2, st) + np_pw_sq(a + (long)n2*st, n - n2, st);
}

// ======== phase 0: fsq via 4-leaf parallel np tree; center row 0; rows 1..3 = 0
// np_pw_sq(512) == (pw(128)+pw(128)) + (pw(128)+pw(128))  — exact numpy split.
__global__ __launch_bounds__(NTHR)
void k_prep(const float* __restrict__ X, float* __restrict__ C, float* __restrict__ fsq){
  const int blk = blockIdx.x, tid = threadIdx.x;
  const int q = tid >> 6, l = tid & 63;    // wave = quarter, lane = point
  __shared__ float red[4][64];

  const int P = blk*64 + l;                // 1000*64 = 64000 points
  const int bf = P / NPTS, gf = P - bf*NPTS;
  const int nf = gf / TLEN, tf = gf - nf*TLEN;
  red[q][l] = np_pw_sq(X + ((size_t)(bf*NSPK_ + nf)*DIMS + q*128)*TLEN + tf, 128, TLEN);
  __syncthreads();
  if (tid < 64)
    fsq[blk*64 + tid] = (red[0][tid] + red[1][tid]) + (red[2][tid] + red[3][tid]);

  if (blk < NBATCH){
    for (int d = tid; d < DIMS; d += NTHR)
      C[blk*KC*DIMS + d] = X[((size_t)(blk*NSPK_)*DIMS + d)*TLEN];
  } else if (blk < 2*NBATCH){
    int bb = blk - NBATCH;
    for (int e = tid; e < 3*DIMS; e += NTHR) C[bb*KC*DIMS + DIMS + e] = 0.f;
  }
}

// ======== init dist: dmin over all 4 rows (zero rows give fsq == reference :i+1 slice)
__global__ __launch_bounds__(NTHR)
void k_dist(const float* __restrict__ X, const float* __restrict__ C,
            const float* __restrict__ fsq, float* __restrict__ dmin){
  const int blk = blockIdx.x, tid = threadIdx.x;
  const int w = tid >> 6, l = tid & 63;
  const int b = blk / BPB;
  const int P = blk*PPB + l;
  const int g = P - b*NPTS;
  const int n = g / TLEN, t = g - n*TLEN;

  __shared__ __align__(16) float cent[DIMS*KC];
  __shared__ float red[4][KC][PPB];
  __shared__ float csq_s[KC];

  const float* Cb = C + b*KC*DIMS;
  #pragma unroll
  for (int j = 0; j < 8; ++j){
    int e = tid*8 + j;
    cent[e] = Cb[(e&3)*DIMS + (e>>2)];
  }
  { const float* ck = Cb + w*DIMS + l*8;
    float s = 0.f;
    #pragma unroll
    for (int j = 0; j < 8; ++j){ float c = ck[j]; s += c*c; }
    #pragma unroll
    for (int o = 32; o; o >>= 1) s += __shfl_xor(s, o, 64);
    if (l == 0) csq_s[w] = s;
  }
  __syncthreads();

  const float* xp = X + (((size_t)(b*NSPK_ + n)*DIMS) + w*128)*TLEN + t;
  const float4* c4p = (const float4*)cent + w*128;
  float a0=0,a1=0,a2=0,a3=0;
  #pragma unroll 8
  for (int dq = 0; dq < 128; ++dq){
    float x = xp[(size_t)dq*TLEN];
    float4 c = c4p[dq];
    a0 += x*c.x; a1 += x*c.y; a2 += x*c.z; a3 += x*c.w;
  }
  red[w][0][l]=a0; red[w][1][l]=a1; red[w][2][l]=a2; red[w][3][l]=a3;
  __syncthreads();
  if (tid < PPB){
    float A0 = red[0][0][l]+red[1][0][l]+red[2][0][l]+red[3][0][l];
    float A1 = red[0][1][l]+red[1][1][l]+red[2][1][l]+red[3][1][l];
    float A2 = red[0][2][l]+red[1][2][l]+red[2][2][l]+red[3][2][l];
    float A3 = red[0][3][l]+red[1][3][l]+red[2][3][l]+red[3][3][l];
    float fs = fsq[P];
    float dm = (fs + csq_s[0]) - 2.f*A0;
    dm = fminf(dm, (fs + csq_s[1]) - 2.f*A1);
    dm = fminf(dm, (fs + csq_s[2]) - 2.f*A2);
    dm = fminf(dm, (fs + csq_s[3]) - 2.f*A3);
    dmin[P] = dm;
  }
}

// ======== selection (np-exact): grid 8, one block per batch; writes center row i
__global__ __launch_bounds__(NTHR)
void k_select(const float* __restrict__ X, float* __restrict__ C,
              const float* __restrict__ dmin, RArg ra, int i){
  const int bs = blockIdx.x, tid = threadIdx.x;
  const int w = tid >> 6, l = tid & 63;
  __shared__ __align__(16) float sbuf[NPTS];   // 32 KB
  __shared__ __align__(16) float pbuf[NPTS];   // 32 KB
  __shared__ float fsh[1];
  __shared__ int   ired[4];
  float rT = ra.r[i-1][bs];

  for (int e = tid; e < NPTS; e += NTHR) sbuf[e] = dmin[bs*NPTS + e];
  __syncthreads();
  // np.sum(8000): exact pairwise tree = 64 leaves (8 per 1000-chunk, numpy's
  // n2-=n2&7 split) combined by a perfect binary tree; xor-butterfly lane 0
  // reproduces the exact left-first pairing at every level.
  if (w == 0){
    const int chunk = l >> 3, idx = l & 7;
    const int offs[8] = {0,120,248,368,496,616,744,872};
    int off = chunk*1000 + offs[idx];
    int len = (idx==0 || idx==2 || idx==4) ? 120 : 128;
    float v = np_pw(sbuf + off, len, 1);
    #pragma unroll
    for (int o = 1; o < 64; o <<= 1) v = v + __shfl_xor(v, o, 64);
    if (l == 0) fsh[0] = v;
  }
  __syncthreads();
  float tot = fsh[0];
  for (int e = tid; e < NPTS; e += NTHR) sbuf[e] = sbuf[e] / tot;  // IEEE div like np
  __syncthreads();
  // serial fp32 prefix: software-pipelined (load batch j+1 during adds of batch j)
  if (tid == 0){
    #pragma clang fp contract(off)
    float b0[32], b1[32];
    #pragma unroll
    for (int u = 0; u < 32; ++u) b0[u] = sbuf[u];
    float run = 0.f;
    for (int j = 0; j < NPTS; j += 64){
      #pragma unroll
      for (int u = 0; u < 32; ++u) b1[u] = sbuf[j + 32 + u];
      #pragma unroll
      for (int u = 0; u < 32; ++u){ run = run + b0[u]; pbuf[j + u] = run; }
      if (j + 64 < NPTS){
        #pragma unroll
        for (int u = 0; u < 32; ++u) b0[u] = sbuf[j + 64 + u];
      }
      #pragma unroll
      for (int u = 0; u < 32; ++u){ run = run + b1[u]; pbuf[j + 32 + u] = run; }
    }
  }
  __syncthreads();
  int cnt = 0;
  for (int e = tid; e < NPTS; e += NTHR) cnt += (pbuf[e] <= rT) ? 1 : 0;
  #pragma unroll
  for (int o = 32; o; o >>= 1) cnt += __shfl_xor(cnt, o, 64);
  if (l == 0) ired[w] = cnt;
  __syncthreads();
  int sel = (ired[0] + ired[1] + ired[2] + ired[3]) - 1;
  for (int d = tid; d < DIMS; d += NTHR){
    float v = 0.f;
    if (sel >= 0){
      int ns = sel / TLEN, ts = sel - ns*TLEN;
      v = X[((size_t)(bs*NSPK_ + ns)*DIMS + d)*TLEN + ts];
    }
    C[(bs*KC + i)*DIMS + d] = v;
  }
}

// ======== Lloyd iteration: 4 rounds x 16 points, 36 KB LDS -> 4 blocks/CU
// thread = (dgg = tid>>2 in 0..63, pq = tid&3); d = dd*64 + dgg (dd 0..7)
__global__ __launch_bounds__(NTHR, 4)
void k_iter(const float* __restrict__ X, const float* __restrict__ C,
            const float* __restrict__ fsq, float* __restrict__ part,
            int* __restrict__ pnum){
  const int blk = blockIdx.x, tid = threadIdx.x;
  const int w = tid >> 6, l = tid & 63;
  const int pq = tid & 3;
  const int dgg = tid >> 2;                 // 0..63
  const int b = blk / BPB;
  const int g0 = (blk - b*BPB)*PPB;

  __shared__ float tile[DIMS*TS2];               // 34.8 KB [d*17 + col]
  __shared__ __align__(16) float red2[4][4][16]; // 1 KB [wave][pq][pt(4)*... 4 f4]
  __shared__ int   ks[16];
  __shared__ float csq_s[KC];
  __shared__ int   cntk[KC];

  // csq (mean scale 1/512): wave w computes cluster w
  const float* Cb = C + b*KC*DIMS;
  { const float* ck = Cb + w*DIMS + l*8;
    float s = 0.f;
    #pragma unroll
    for (int j = 0; j < 8; ++j){ float c = ck[j]; s += c*c; }
    #pragma unroll
    for (int o = 32; o; o >>= 1) s += __shfl_xor(s, o, 64);
    if (l == 0) csq_s[w] = s * (1.f/512.f);
  }
  if (tid < KC) cntk[tid] = 0;

  // center registers: cr[dd] = {C[k=0..3][dd*64+dgg]} (C is L2-hot, 64 KB)
  float4 cr[8];
  #pragma unroll
  for (int dd = 0; dd < 8; ++dd){
    int d = dd*64 + dgg;
    cr[dd].x = Cb[0*DIMS + d];
    cr[dd].y = Cb[1*DIMS + d];
    cr[dd].z = Cb[2*DIMS + d];
    cr[dd].w = Cb[3*DIMS + d];
  }

  float s00=0,s01=0,s02=0,s03=0, s10=0,s11=0,s12=0,s13=0;
  const int d0 = tid, d1 = tid + 256;

  for (int h = 0; h < 4; ++h){
    const int gp = g0 + h*16 + pq*4;          // 2000%4==0 -> quad never straddles n
    const int n = gp / TLEN, t = gp - n*TLEN;
    const float* xr = X + ((size_t)(b*NSPK_ + n)*DIMS + dgg)*TLEN + t;
    float4 a0 = {0,0,0,0}, a1 = {0,0,0,0}, a2 = {0,0,0,0}, a3 = {0,0,0,0};
    #pragma unroll
    for (int dd = 0; dd < 8; ++dd){
      float4 x4 = *(const float4*)(xr + (size_t)dd*64*TLEN);
      int dw = (dd*64 + dgg)*TS2 + pq*4;
      tile[dw+0] = x4.x; tile[dw+1] = x4.y; tile[dw+2] = x4.z; tile[dw+3] = x4.w;
      float4 c = cr[dd];
      a0.x += x4.x*c.x; a0.y += x4.x*c.y; a0.z += x4.x*c.z; a0.w += x4.x*c.w;
      a1.x += x4.y*c.x; a1.y += x4.y*c.y; a1.z += x4.y*c.z; a1.w += x4.y*c.w;
      a2.x += x4.z*c.x; a2.y += x4.z*c.y; a2.z += x4.z*c.z; a2.w += x4.z*c.w;
      a3.x += x4.w*c.x; a3.y += x4.w*c.y; a3.z += x4.w*c.z; a3.w += x4.w*c.w;
    }
    // reduce over the 16 dgg-lanes sharing pq within this wave (fixed order)
    #pragma unroll
    for (int o = 4; o <= 32; o <<= 1){
      a0.x += __shfl_xor(a0.x,o,64); a0.y += __shfl_xor(a0.y,o,64);
      a0.z += __shfl_xor(a0.z,o,64); a0.w += __shfl_xor(a0.w,o,64);
      a1.x += __shfl_xor(a1.x,o,64); a1.y += __shfl_xor(a1.y,o,64);
      a1.z += __shfl_xor(a1.z,o,64); a1.w += __shfl_xor(a1.w,o,64);
      a2.x += __shfl_xor(a2.x,o,64); a2.y += __shfl_xor(a2.y,o,64);
      a2.z += __shfl_xor(a2.z,o,64); a2.w += __shfl_xor(a2.w,o,64);
      a3.x += __shfl_xor(a3.x,o,64); a3.y += __shfl_xor(a3.y,o,64);
      a3.z += __shfl_xor(a3.z,o,64); a3.w += __shfl_xor(a3.w,o,64);
    }
    if ((tid & 60) == 0){                      // lanes 0..3 of each wave (dgg_loc=0)
      float4* r4 = (float4*)&red2[w][pq][0];
      r4[0] = a0; r4[1] = a1; r4[2] = a2; r4[3] = a3;
    }
    __syncthreads();
    if (tid < 16){
      int p = tid, pqq = p >> 2, j = p & 3;
      float4 A = {0,0,0,0};
      #pragma unroll
      for (int q = 0; q < 4; ++q){
        float4 v = ((const float4*)&red2[q][pqq][0])[j];
        A.x += v.x; A.y += v.y; A.z += v.z; A.w += v.w;
      }
      float xs = fsq[b*NPTS + g0 + h*16 + p] * (1.f/512.f);
      float e0 = (xs + csq_s[0]) - 2.f*(A.x*(1.f/512.f));
      float e1 = (xs + csq_s[1]) - 2.f*(A.y*(1.f/512.f));
      float e2 = (xs + csq_s[2]) - 2.f*(A.z*(1.f/512.f));
      float e3 = (xs + csq_s[3]) - 2.f*(A.w*(1.f/512.f));
      int bi = 0; float bv = e0;            // first-min == np.argmin
      if (e1 < bv){ bv = e1; bi = 1; }
      if (e2 < bv){ bv = e2; bi = 2; }
      if (e3 < bv){ bv = e3; bi = 3; }
      ks[p] = bi;
      unsigned long long m0 = __ballot(bi==0), m1 = __ballot(bi==1);
      unsigned long long m2 = __ballot(bi==2), m3 = __ballot(bi==3);
      if (p == 0){
        cntk[0] += __popcll(m0); cntk[1] += __popcll(m1);
        cntk[2] += __popcll(m2); cntk[3] += __popcll(m3);
      }
    }
    __syncthreads();
    // cluster sums from tile (thread <-> d, wave-uniform k), <=2-way banks (free)
    #pragma unroll 4
    for (int p2 = 0; p2 < 16; ++p2){
      int kk = __builtin_amdgcn_readfirstlane(ks[p2]);
      float x0 = tile[d0*TS2 + p2];
      float x1 = tile[d1*TS2 + p2];
      if (kk == 0){ s00 += x0; s10 += x1; }
      else if (kk == 1){ s01 += x0; s11 += x1; }
      else if (kk == 2){ s02 += x0; s12 += x1; }
      else { s03 += x0; s13 += x1; }
    }
    __syncthreads();   // tile/red2/ks reused next round
  }

  if (tid < KC) pnum[blk*4 + tid] = cntk[tid];
  part[((size_t)blk*KC + 0)*DIMS + d0] = s00;
  part[((size_t)blk*KC + 1)*DIMS + d0] = s01;
  part[((size_t)blk*KC + 2)*DIMS + d0] = s02;
  part[((size_t)blk*KC + 3)*DIMS + d0] = s03;
  part[((size_t)blk*KC + 0)*DIMS + d1] = s10;
  part[((size_t)blk*KC + 1)*DIMS + d1] = s11;
  part[((size_t)blk*KC + 2)*DIMS + d1] = s12;
  part[((size_t)blk*KC + 3)*DIMS + d1] = s13;
}

// ======== reduce partials -> centers. grid 256: blk = (bb*4+k)*8 + seg(64 d's)
__global__ __launch_bounds__(NTHR)
void k_reduce(const float* __restrict__ part, const int* __restrict__ pnum,
              float* __restrict__ C){
  const int blk = blockIdx.x, tid = threadIdx.x;
  const int seg = blk & 7, bk = blk >> 3;
  const int bb = bk >> 2, k = bk & 3;
  const int w = tid >> 6, l = tid & 63;
  __shared__ float red[4][64];
  __shared__ int ns[4];

  int v = 0;
  if (tid < BPB) v = pnum[(bb*BPB + tid)*4 + k];
  #pragma unroll
  for (int o = 32; o; o >>= 1) v += __shfl_xor(v, o, 64);
  if (l == 0) ns[w] = v;
  __syncthreads();
  float den = (float)(ns[0]+ns[1]+ns[2]+ns[3]) + 1e-8f;

  int jb = (BPB*w) >> 2, je = (BPB*(w+1)) >> 2;   // fixed quarters of 125
  float s = 0.f;
  for (int j = jb; j < je; ++j)
    s += part[((size_t)(bb*BPB + j)*KC + k)*DIMS + seg*64 + l];
  red[w][l] = s;
  __syncthreads();
  if (tid < 64){
    float tsum = red[0][l] + red[1][l] + red[2][l] + red[3][l];
    C[bk*DIMS + seg*64 + l] = tsum / den;
  }
}

// ======================= host: threefry2x32 (JAX-compatible) =======================
static inline uint32_t rotl_(uint32_t x, int r){ return (x << r) | (x >> (32 - r)); }
static void tf2x32(uint32_t k0, uint32_t k1, uint32_t x0, uint32_t x1,
                   uint32_t* o0, uint32_t* o1){
  static const int R0[4] = {13,15,26,6}, R1[4] = {17,29,16,24};
  uint32_t ks[3] = { k0, k1, k0 ^ k1 ^ 0x1BD11BDAu };
  x0 += ks[0]; x1 += ks[1];
  for (int g = 0; g < 5; ++g){
    const int* rot = (g & 1) ? R1 : R0;
    for (int r = 0; r < 4; ++r){ x0 += x1; x1 = rotl_(x1, rot[r]); x1 ^= x0; }
    x0 += ks[(g+1)%3];
    x1 += ks[(g+2)%3] + (uint32_t)(g+1);
  }
  *o0 = x0; *o1 = x1;
}
static float tf_uniform_bits(uint32_t bits){
  uint32_t u = (bits >> 9) | 0x3f800000u;
  float f; memcpy(&f, &u, 4);
  return f - 1.0f;
}

extern "C" void kernel_launch(void* const* d_in, const int* in_sizes, int n_in,
                              void* d_out, int out_size, void* d_ws, size_t ws_size,
                              hipStream_t stream) {
  (void)in_sizes; (void)n_in; (void)out_size; (void)ws_size;
  const float* X = (const float*)d_in[0];
  float* centers = (float*)d_out;                 // (8,4,512)

  char* w = (char*)d_ws;
  float* fsq  = (float*)w;  w += (size_t)NBATCH*NPTS*4;            // 256 KB
  float* dmin = (float*)w;  w += (size_t)NBATCH*NPTS*4;            // 256 KB
  float* part = (float*)w;  w += (size_t)NBLK*KC*DIMS*4;           // 8.2 MB
  int*   pnum = (int*)w;    w += (size_t)NBLK*KC*4;                // 16 KB

  RArg ra;
  uint32_t k0 = 0u, k1 = 1u;
  for (int i = 0; i < 3; ++i){
#if THREEFRY_PARTITIONABLE
    uint32_t nk0, nk1, s0, s1;
    tf2x32(k0, k1, 0u, 0u, &nk0, &nk1);
    tf2x32(k0, k1, 0u, 1u, &s0, &s1);
    k0 = nk0; k1 = nk1;
    for (int bq = 0; bq < NBATCH; ++bq){
      uint32_t b1v, b2v; tf2x32(s0, s1, 0u, (uint32_t)bq, &b1v, &b2v);
      ra.r[i][bq] = tf_uniform_bits(b1v ^ b2v);
    }
#else
    uint32_t a0, b0, a1, b1;
    tf2x32(k0, k1, 0u, 2u, &a0, &b0);
    tf2x32(k0, k1, 1u, 3u, &a1, &b1);
    uint32_t s0 = b0, s1 = b1;
    k0 = a0; k1 = a1;
    uint32_t bits[8];
    for (int j = 0; j < 4; ++j){
      uint32_t c, d2; tf2x32(s0, s1, (uint32_t)j, (uint32_t)(j+4), &c, &d2);
      bits[j] = c; bits[j+4] = d2;
    }
    for (int bq = 0; bq < NBATCH; ++bq) ra.r[i][bq] = tf_uniform_bits(bits[bq]);
#endif
  }

  hipLaunchKernelGGL(k_prep, dim3(NBLK), dim3(NTHR), 0, stream, X, centers, fsq);
  for (int i = 1; i < KC; ++i){
    hipLaunchKernelGGL(k_dist, dim3(NBLK), dim3(NTHR), 0, stream, X, centers, fsq, dmin);
    hipLaunchKernelGGL(k_select, dim3(NBATCH), dim3(NTHR), 0, stream, X, centers, dmin, ra, i);
  }
  for (int it = 0; it < MAXIT; ++it){
    hipLaunchKernelGGL(k_iter, dim3(NBLK), dim3(NTHR), 0, stream, X, centers, fsq, part, pnum);
    hipLaunchKernelGGL(k_reduce, dim3(256), dim3(NTHR), 0, stream, part, pnum, centers);
  }
}